// Round 14
// baseline (116.350 us; speedup 1.0000x reference)
//
#include <hip/hip_runtime.h>
#include <hip/hip_bf16.h>

typedef __attribute__((ext_vector_type(8))) short bf16x8;
typedef __attribute__((ext_vector_type(4))) float f32x4;
typedef __attribute__((ext_vector_type(16))) float f32x16;
typedef __attribute__((ext_vector_type(2))) unsigned uint2v;

__device__ __forceinline__ ushort f2bf(float f) {
  union { float f; unsigned u; } v; v.f = f;
  unsigned r = v.u + 0x7FFFu + ((v.u >> 16) & 1u);
  return (ushort)(r >> 16);
}

__device__ __forceinline__ float exp2_(float x) {
#if __has_builtin(__builtin_amdgcn_exp2f)
  return __builtin_amdgcn_exp2f(x);
#else
  return exp2f(x);
#endif
}

__device__ __forceinline__ unsigned cvtpk(float lo, float hi) {
  unsigned r;
  asm("v_cvt_pk_bf16_f32 %0, %1, %2" : "=v"(r) : "v"(lo), "v"(hi));
  return r;
}

__device__ __forceinline__ uint2v lane32_swap(unsigned a, unsigned b) {
#if __has_builtin(__builtin_amdgcn_permlane32_swap)
  return __builtin_amdgcn_permlane32_swap(a, b, false, false);
#else
  unsigned sa = (unsigned)__shfl_xor((int)a, 32);
  unsigned sb = (unsigned)__shfl_xor((int)b, 32);
  bool lo = ((threadIdx.x & 32) == 0);
  uint2v r;
  r.x = lo ? a : sb;
  r.y = lo ? sa : b;
  return r;
#endif
}

// async global -> LDS, 16B per lane (wave-uniform LDS base + lane*16)
__device__ __forceinline__ void gload_lds16(const ushort* g, ushort* l) {
  __builtin_amdgcn_global_load_lds(
      (const __attribute__((address_space(1))) void*)g,
      (__attribute__((address_space(3))) void*)l, 16, 0, 0);
}

template <int N>
__device__ __forceinline__ void vmw() {
  asm volatile("s_waitcnt vmcnt(%0)" ::"i"(N) : "memory");
}

// 0.125 * log2(e): fold softmax scale + exp->exp2 conversion into Q
#define QSCALE 0.18033688011112042f

// ---------------------------------------------------------------- merged prep
__global__ void __launch_bounds__(256) prep_kernel(
    const float* __restrict__ H, const float* __restrict__ WQ,
    const float* __restrict__ WK, const float* __restrict__ WV,
    const float* __restrict__ WO, ushort* __restrict__ Hb,
    ushort* __restrict__ Wqkv, ushort* __restrict__ Wo) {
  int bid = blockIdx.x;
  if (bid < 4096) {
    int i = (bid * 256 + threadIdx.x) * 8;
    float4 a = *(const float4*)(H + i);
    float4 b = *(const float4*)(H + i + 4);
    uint4 o;
    o.x = f2bf(a.x) | ((unsigned)f2bf(a.y) << 16);
    o.y = f2bf(a.z) | ((unsigned)f2bf(a.w) << 16);
    o.z = f2bf(b.x) | ((unsigned)f2bf(b.y) << 16);
    o.w = f2bf(b.z) | ((unsigned)f2bf(b.w) << 16);
    *(uint4*)(Hb + i) = o;
  } else if (bid < 7168) {
    int t = (bid - 4096) * 256 + threadIdx.x;
    int j = t >> 9, d = t & 511;
    int m = j / 192, r = j % 192, which = r >> 6, dk = r & 63;
    const float* W = (which == 0) ? WQ : (which == 1) ? WK : WV;
    Wqkv[t] = f2bf(W[(m * 512 + d) * 64 + dk]);
  } else {
    int t = (bid - 7168) * 256 + threadIdx.x;
    int j = t >> 9, mv = t & 511;
    Wo[t] = f2bf(WO[mv * 512 + j]);
  }
}

// ---------------------------------------------------------------- pipelined GEMM v3
// A[M][512] @ Bt[N][512]^T, BM=BN=128, BK=32 (16 K-tiles). One phase/tile:
// 8 ds_read -> drain -> barrier -> STAGE(t+2 into freed buf) -> 16 MFMA
// -> counted vmw<4> -> barrier. LDS 32KB total (2 buf x [128][32] x A,B) ->
// 4-5 blocks/CU (was 2 at BK=64): cross-block overlap hides the per-tile
// latency chain. Chunk swizzle c ^= (r>>1)&3 (involution, 2-way bank = free).
// REQUIRES Kdim == 512. EPI==0: C fp32. EPI==1: scatter Q/K/V bf16.
template <int EPI>
__global__ void __launch_bounds__(256, 4) gemm_bt_pipe(
    const ushort* __restrict__ A, const ushort* __restrict__ Bt,
    float* __restrict__ C, int Kdim, int Ncols,
    ushort* __restrict__ Qo, ushort* __restrict__ Ko, ushort* __restrict__ Vo) {
  __shared__ __align__(16) ushort S[16384];
  ushort* SA = S;            // [2 buf][128 rows][32 elems]
  ushort* SB = S + 8192;

  const int tid = threadIdx.x, lane = tid & 63, w = tid >> 6;
  const int hs = lane >> 4, l15 = lane & 15;
  const int wm = w >> 1, wn = w & 1;

  // XCD-bijective swizzle of linear block id (nwg % 8 == 0 for both uses)
  const int gx = gridDim.x;
  const int nwg = gx * gridDim.y;
  const int bid = blockIdx.y * gx + blockIdx.x;
  const int id2 = (bid & 7) * (nwg >> 3) + (bid >> 3);
  const int brow = (id2 / gx) * 128, bcol = (id2 % gx) * 128;

  // staging map: gload g covers rows g*64 + (tid>>2), chunk lane&3; source
  // chunk pre-swizzled: (lane&3) ^ ((row>>1)&3), (row>>1)&3 == (lane>>3)&3
  const int srow = tid >> 2;
  const int sslot = ((lane & 3) ^ ((lane >> 3) & 3)) * 8;
  const ushort* aS = A + (size_t)(brow + srow) * Kdim + sslot;
  const ushort* bS = Bt + (size_t)(bcol + srow) * Kdim + sslot;

  f32x4 acc[4][4];
  const f32x4 z4 = {0.f, 0.f, 0.f, 0.f};
#pragma unroll
  for (int i = 0; i < 4; ++i)
#pragma unroll
    for (int j = 0; j < 4; ++j) acc[i][j] = z4;

  // stage full 128x32 A and B tiles of K-tile T into buffer buf (4 gload_lds)
  auto STAGE = [&](int T, int buf) {
    ushort* la = SA + buf * 4096 + (w * 16) * 32;
    ushort* lb = SB + buf * 4096 + (w * 16) * 32;
#pragma unroll
    for (int g = 0; g < 2; ++g) {
      gload_lds16(aS + T * 32 + (size_t)(g * 64) * Kdim, la + g * 64 * 32);
      gload_lds16(bS + T * 32 + (size_t)(g * 64) * Kdim, lb + g * 64 * 32);
    }
  };

  // read fragments (8 ds_read_b128); read chunk = hs ^ ((row>>1)&3)
  auto LOADF = [&](int buf, bf16x8* af, bf16x8* bf) {
    const ushort* Ab = SA + buf * 4096;
    const ushort* Bb = SB + buf * 4096;
#pragma unroll
    for (int fr = 0; fr < 4; ++fr) {
      int r = wm * 64 + fr * 16 + l15;
      int c = hs ^ ((r >> 1) & 3);
      af[fr] = *(const bf16x8*)&Ab[r * 32 + c * 8];
    }
#pragma unroll
    for (int fc = 0; fc < 4; ++fc) {
      int r = wn * 64 + fc * 16 + l15;
      int c = hs ^ ((r >> 1) & 3);
      bf[fc] = *(const bf16x8*)&Bb[r * 32 + c * 8];
    }
  };

  // prologue: stage tiles 0 and 1; retire tile 0 (counted, tile 1 in flight)
  STAGE(0, 0);
  STAGE(1, 1);
  vmw<4>();
  __builtin_amdgcn_s_barrier();

#pragma unroll
  for (int t = 0; t < 16; ++t) {
    const int buf = t & 1;
    bf16x8 af[4], bf[4];
    LOADF(buf, af, bf);
    // drain this wave's ds_reads into registers before any wave overwrites buf
    asm volatile("s_waitcnt lgkmcnt(0)" ::: "memory");
    __builtin_amdgcn_sched_barrier(0);
    __builtin_amdgcn_s_barrier();          // all waves' reads of buf complete
    if (t < 14) STAGE(t + 2, buf);         // overwrite freed buffer
    __builtin_amdgcn_s_setprio(1);
#pragma unroll
    for (int i = 0; i < 4; ++i)
#pragma unroll
      for (int j = 0; j < 4; ++j)
        acc[i][j] = __builtin_amdgcn_mfma_f32_16x16x32_bf16(af[i], bf[j], acc[i][j], 0, 0, 0);
    __builtin_amdgcn_s_setprio(0);
    // retire tile t+1's stage before next iteration reads it (counted)
    if (t < 14) vmw<4>(); else if (t == 14) vmw<0>();
    __builtin_amdgcn_s_barrier();
  }

#pragma unroll
  for (int i = 0; i < 4; ++i) {
    int row0 = brow + wm * 64 + i * 16 + hs * 4;
#pragma unroll
    for (int j = 0; j < 4; ++j) {
      int col = bcol + wn * 64 + j * 16 + l15;
      if (EPI == 0) {
#pragma unroll
        for (int q = 0; q < 4; ++q)
          C[(size_t)(row0 + q) * Ncols + col] = acc[i][j][q];
      } else {
        int m = col / 192, r = col % 192, which = r >> 6, dk = r & 63;
        ushort* base = (which == 0) ? Qo : (which == 1) ? Ko : Vo;
        float cs = (which == 0) ? QSCALE : 1.0f;
#pragma unroll
        for (int q = 0; q < 4; ++q) {
          int row = row0 + q;
          int bb = row >> 10, n = row & 1023;
          base[(size_t)((bb * 8 + m) * 1024 + n) * 64 + dk] = f2bf(acc[i][j][q] * cs);
        }
      }
    }
  }
}

// ---------------------------------------------------------------- V transpose
__global__ void __launch_bounds__(256) transpose_v_kernel(const ushort* __restrict__ V,
                                                          ushort* __restrict__ Vt) {
  __shared__ __align__(16) ushort T[64][72];
  int bm = blockIdx.x >> 4, nt = blockIdx.x & 15;
  const ushort* src = V + (size_t)bm * 65536 + nt * 64 * 64;
  int tid = threadIdx.x;
#pragma unroll
  for (int i = 0; i < 2; ++i) {
    int c = tid + i * 256;
    int row = c >> 3, cc = (c & 7) * 8;
    *(uint4*)&T[row][cc] = *(const uint4*)(src + c * 8);
  }
  __syncthreads();
  int v = tid >> 2, nn0 = (tid & 3) * 16;
  ushort tmp[16];
#pragma unroll
  for (int k = 0; k < 16; ++k) tmp[k] = T[nn0 + k][v];
  ushort* dst = Vt + (size_t)bm * 65536 + v * 1024 + nt * 64 + nn0;
  *(uint4*)(dst + 0) = *(uint4*)&tmp[0];
  *(uint4*)(dst + 8) = *(uint4*)&tmp[8];
}

// ---------------------------------------------------------------- flash attention v6
// (byte-identical to round 7/11/13: QBLK=64/wave, swapped QK^T, branchless
// no-max softmax in exp2 domain, l via all-ones MFMA on the matrix pipe)
__global__ void __launch_bounds__(256, 2) attn_kernel(const ushort* __restrict__ Q,
                                                      const ushort* __restrict__ K,
                                                      const ushort* __restrict__ Vt,
                                                      ushort* __restrict__ Hp) {
  __shared__ __align__(16) ushort Ks[2][64 * 64];
  __shared__ __align__(16) ushort Vs[2][64 * 64];

  int wk = (blockIdx.x & 7) * 64 + (blockIdx.x >> 3);
  const int bm = wk >> 2, qt = wk & 3;
  const int b = bm >> 3, m = bm & 7;
  const int tid = threadIdx.x, lane = tid & 63, w = tid >> 6;
  const int hi = lane >> 5, l31 = lane & 31;
  const ushort* Qp = Q + (size_t)bm * 65536;
  const ushort* Kp = K + (size_t)bm * 65536;
  const ushort* Vp = Vt + (size_t)bm * 65536;
  const int qw = qt * 256 + w * 64;

  bf16x8 qb[2][4];
#pragma unroll
  for (int qs = 0; qs < 2; ++qs)
#pragma unroll
    for (int s = 0; s < 4; ++s)
      qb[qs][s] = *(const bf16x8*)(Qp + (size_t)(qw + qs * 32 + l31) * 64 + s * 16 + hi * 8);

  bf16x8 ones;
#pragma unroll
  for (int j = 0; j < 8; ++j) ones[j] = (short)0x3F80;

  f32x16 oacc[2][2], lacc[2];
#pragma unroll
  for (int r = 0; r < 16; ++r) {
    oacc[0][0][r] = 0.f; oacc[0][1][r] = 0.f;
    oacc[1][0][r] = 0.f; oacc[1][1][r] = 0.f;
    lacc[0][r] = 0.f; lacc[1][r] = 0.f;
  }

  const int sr = tid >> 2, sc4 = (tid & 3) << 4;
  const unsigned bo0 = ((unsigned)(sc4 * 2)) ^ (((unsigned)(sr & 7)) << 4);

  {
    uint4 k0 = *(const uint4*)(Kp + (size_t)sr * 64 + sc4);
    uint4 k1 = *(const uint4*)(Kp + (size_t)sr * 64 + sc4 + 8);
    uint4 v0 = *(const uint4*)(Vp + (size_t)sr * 1024 + sc4);
    uint4 v1 = *(const uint4*)(Vp + (size_t)sr * 1024 + sc4 + 8);
    char* kd = (char*)&Ks[0][sr * 64];
    char* vd = (char*)&Vs[0][sr * 64];
    *(uint4*)(kd + bo0) = k0; *(uint4*)(kd + (bo0 ^ 16)) = k1;
    *(uint4*)(vd + bo0) = v0; *(uint4*)(vd + (bo0 ^ 16)) = v1;
  }
  __syncthreads();

  int cur = 0;
  for (int kt = 0; kt < 16; ++kt) {
    uint4 k0, k1, v0, v1;
    const bool pf = (kt < 15);
    if (pf) {
      int n0 = (kt + 1) * 64;
      k0 = *(const uint4*)(Kp + (size_t)(n0 + sr) * 64 + sc4);
      k1 = *(const uint4*)(Kp + (size_t)(n0 + sr) * 64 + sc4 + 8);
      v0 = *(const uint4*)(Vp + (size_t)sr * 1024 + n0 + sc4);
      v1 = *(const uint4*)(Vp + (size_t)sr * 1024 + n0 + sc4 + 8);
    }

    const ushort* kbase = &Ks[cur][0];
    bf16x8 kA[2][4];
#pragma unroll
    for (int ja = 0; ja < 2; ++ja) {
      int row = ja * 32 + l31;
      const char* kr = (const char*)(kbase + row * 64);
#pragma unroll
      for (int s = 0; s < 4; ++s)
        kA[ja][s] = *(const bf16x8*)(kr + (((unsigned)(s * 32 + hi * 16)) ^ (((unsigned)(row & 7)) << 4)));
    }

    f32x16 st[2][2];
#pragma unroll
    for (int qs = 0; qs < 2; ++qs)
#pragma unroll
      for (int ja = 0; ja < 2; ++ja) {
#pragma unroll
        for (int r = 0; r < 16; ++r) st[qs][ja][r] = 0.f;
#pragma unroll
        for (int s = 0; s < 4; ++s)
          st[qs][ja] = __builtin_amdgcn_mfma_f32_32x32x16_bf16(kA[ja][s], qb[qs][s], st[qs][ja], 0, 0, 0);
      }

    bf16x8 pb[2][4];
#pragma unroll
    for (int qs = 0; qs < 2; ++qs) {
#pragma unroll
      for (int r = 0; r < 16; ++r) {
        st[qs][0][r] = exp2_(st[qs][0][r]);
        st[qs][1][r] = exp2_(st[qs][1][r]);
      }

#pragma unroll
      for (int ja = 0; ja < 2; ++ja) {
#pragma unroll
        for (int g = 0; g < 2; ++g) {
          unsigned x0 = cvtpk(st[qs][ja][g * 8 + 0], st[qs][ja][g * 8 + 1]);
          unsigned x1 = cvtpk(st[qs][ja][g * 8 + 2], st[qs][ja][g * 8 + 3]);
          unsigned y0 = cvtpk(st[qs][ja][g * 8 + 4], st[qs][ja][g * 8 + 5]);
          unsigned y1 = cvtpk(st[qs][ja][g * 8 + 6], st[qs][ja][g * 8 + 7]);
          uint2v s0 = lane32_swap(x0, y0);
          uint2v s1 = lane32_swap(x1, y1);
          uint4 wv; wv.x = s0.x; wv.y = s1.x; wv.z = s0.y; wv.w = s1.y;
          pb[qs][ja * 2 + g] = *(bf16x8*)&wv;
        }
      }

#pragma unroll
      for (int ks = 0; ks < 4; ++ks)
        lacc[qs] = __builtin_amdgcn_mfma_f32_32x32x16_bf16(ones, pb[qs][ks], lacc[qs], 0, 0, 0);
    }

    const ushort* vbase = &Vs[cur][0];
#pragma unroll
    for (int vj = 0; vj < 2; ++vj) {
      int row = vj * 32 + l31;
      const char* vr = (const char*)(vbase + row * 64);
      bf16x8 va[4];
#pragma unroll
      for (int ks = 0; ks < 4; ++ks)
        va[ks] = *(const bf16x8*)(vr + (((unsigned)(ks * 32 + hi * 16)) ^ (((unsigned)(row & 7)) << 4)));
#pragma unroll
      for (int qs = 0; qs < 2; ++qs)
#pragma unroll
        for (int ks = 0; ks < 4; ++ks)
          oacc[qs][vj] = __builtin_amdgcn_mfma_f32_32x32x16_bf16(va[ks], pb[qs][ks], oacc[qs][vj], 0, 0, 0);
    }

    if (pf) {
      char* kd = (char*)&Ks[cur ^ 1][sr * 64];
      char* vd = (char*)&Vs[cur ^ 1][sr * 64];
      *(uint4*)(kd + bo0) = k0; *(uint4*)(kd + (bo0 ^ 16)) = k1;
      *(uint4*)(vd + bo0) = v0; *(uint4*)(vd + (bo0 ^ 16)) = v1;
    }
    __syncthreads();
    cur ^= 1;
  }

#pragma unroll
  for (int qs = 0; qs < 2; ++qs) {
    float linv = 1.0f / lacc[qs][0];
    int q = qw + qs * 32 + l31;
    size_t ro = ((size_t)b * 1024 + q) * 512 + m * 64;
#pragma unroll
    for (int vj = 0; vj < 2; ++vj)
#pragma unroll
      for (int t4 = 0; t4 < 4; ++t4) {
        ushort4 o;
        o.x = f2bf(oacc[qs][vj][t4 * 4 + 0] * linv);
        o.y = f2bf(oacc[qs][vj][t4 * 4 + 1] * linv);
        o.z = f2bf(oacc[qs][vj][t4 * 4 + 2] * linv);
        o.w = f2bf(oacc[qs][vj][t4 * 4 + 3] * linv);
        *(ushort4*)(Hp + ro + vj * 32 + t4 * 8 + hi * 4) = o;
      }
  }
}

// ---------------------------------------------------------------- launch
extern "C" void kernel_launch(void* const* d_in, const int* in_sizes, int n_in,
                              void* d_out, int out_size, void* d_ws, size_t ws_size,
                              hipStream_t stream) {
  const float* H  = (const float*)d_in[0];
  const float* WQ = (const float*)d_in[1];
  const float* WK = (const float*)d_in[2];
  const float* WV = (const float*)d_in[3];
  const float* WO = (const float*)d_in[4];
  float* out = (float*)d_out;

  ushort* ws   = (ushort*)d_ws;
  ushort* Hb   = ws;                         // 16384*512
  ushort* Wqkv = Hb + 16384 * 512;           // 1536*512
  ushort* Wo   = Wqkv + 1536 * 512;          // 512*512
  ushort* Qb   = Wo + 512 * 512;             // 128*1024*64
  ushort* Kb   = Qb + 128 * 1024 * 64;
  ushort* Vb   = Kb + 128 * 1024 * 64;
  ushort* Vtb  = Vb + 128 * 1024 * 64;
  ushort* Hp   = Vtb + 128 * 1024 * 64;      // 16384*512

  prep_kernel<<<8192, 256, 0, stream>>>(H, WQ, WK, WV, WO, Hb, Wqkv, Wo);
  gemm_bt_pipe<1><<<dim3(12, 128), 256, 0, stream>>>(Hb, Wqkv, nullptr, 512, 1536,
                                                     Qb, Kb, Vb);
  transpose_v_kernel<<<2048, 256, 0, stream>>>(Vb, Vtb);
  attn_kernel<<<512, 256, 0, stream>>>(Qb, Kb, Vtb, Hp);
  gemm_bt_pipe<0><<<dim3(4, 128), 256, 0, stream>>>(Hp, Wo, out, 512, 512,
                                                    nullptr, nullptr, nullptr);
}

// Round 15
// 114.434 us; speedup vs baseline: 1.0167x; 1.0167x over previous
//
#include <hip/hip_runtime.h>
#include <hip/hip_bf16.h>

typedef __attribute__((ext_vector_type(8))) short bf16x8;
typedef __attribute__((ext_vector_type(4))) float f32x4;
typedef __attribute__((ext_vector_type(16))) float f32x16;
typedef __attribute__((ext_vector_type(2))) unsigned uint2v;

__device__ __forceinline__ ushort f2bf(float f) {
  union { float f; unsigned u; } v; v.f = f;
  unsigned r = v.u + 0x7FFFu + ((v.u >> 16) & 1u);
  return (ushort)(r >> 16);
}

__device__ __forceinline__ float exp2_(float x) {
#if __has_builtin(__builtin_amdgcn_exp2f)
  return __builtin_amdgcn_exp2f(x);
#else
  return exp2f(x);
#endif
}

__device__ __forceinline__ unsigned cvtpk(float lo, float hi) {
  unsigned r;
  asm("v_cvt_pk_bf16_f32 %0, %1, %2" : "=v"(r) : "v"(lo), "v"(hi));
  return r;
}

__device__ __forceinline__ uint2v lane32_swap(unsigned a, unsigned b) {
#if __has_builtin(__builtin_amdgcn_permlane32_swap)
  return __builtin_amdgcn_permlane32_swap(a, b, false, false);
#else
  unsigned sa = (unsigned)__shfl_xor((int)a, 32);
  unsigned sb = (unsigned)__shfl_xor((int)b, 32);
  bool lo = ((threadIdx.x & 32) == 0);
  uint2v r;
  r.x = lo ? a : sb;
  r.y = lo ? sa : b;
  return r;
#endif
}

// async global -> LDS, 16B per lane (wave-uniform LDS base + lane*16)
__device__ __forceinline__ void gload_lds16(const ushort* g, ushort* l) {
  __builtin_amdgcn_global_load_lds(
      (const __attribute__((address_space(1))) void*)g,
      (__attribute__((address_space(3))) void*)l, 16, 0, 0);
}

template <int N>
__device__ __forceinline__ void vmw() {
  asm volatile("s_waitcnt vmcnt(%0)" ::"i"(N) : "memory");
}

// 0.125 * log2(e): fold softmax scale + exp->exp2 conversion into Q
#define QSCALE 0.18033688011112042f

// ---------------------------------------------------------------- merged prep
__global__ void __launch_bounds__(256) prep_kernel(
    const float* __restrict__ H, const float* __restrict__ WQ,
    const float* __restrict__ WK, const float* __restrict__ WV,
    const float* __restrict__ WO, ushort* __restrict__ Hb,
    ushort* __restrict__ Wqkv, ushort* __restrict__ Wo) {
  int bid = blockIdx.x;
  if (bid < 4096) {
    int i = (bid * 256 + threadIdx.x) * 8;
    float4 a = *(const float4*)(H + i);
    float4 b = *(const float4*)(H + i + 4);
    uint4 o;
    o.x = f2bf(a.x) | ((unsigned)f2bf(a.y) << 16);
    o.y = f2bf(a.z) | ((unsigned)f2bf(a.w) << 16);
    o.z = f2bf(b.x) | ((unsigned)f2bf(b.y) << 16);
    o.w = f2bf(b.z) | ((unsigned)f2bf(b.w) << 16);
    *(uint4*)(Hb + i) = o;
  } else if (bid < 7168) {
    int t = (bid - 4096) * 256 + threadIdx.x;
    int j = t >> 9, d = t & 511;
    int m = j / 192, r = j % 192, which = r >> 6, dk = r & 63;
    const float* W = (which == 0) ? WQ : (which == 1) ? WK : WV;
    Wqkv[t] = f2bf(W[(m * 512 + d) * 64 + dk]);
  } else {
    int t = (bid - 7168) * 256 + threadIdx.x;
    int j = t >> 9, mv = t & 511;
    Wo[t] = f2bf(WO[mv * 512 + j]);
  }
}

// ---------------------------------------------------------------- pipelined GEMM v2
// A[M][512] @ Bt[N][512]^T, BM=BN=128, BK=64 as ONE phase per K-tile:
// 16 ds_read -> drain -> barrier -> STAGE(t+2 into just-read buf) -> 32 MFMA
// -> counted vmw -> barrier. 2 barriers/K-tile. LDS [2][128][64] with
// 3-bit XOR chunk swizzle (c ^= row&7, involution on both sides).
// REQUIRES Kdim == 512. EPI==0: C fp32. EPI==1: scatter Q/K/V bf16.
template <int EPI>
__global__ void __launch_bounds__(256, 2) gemm_bt_pipe(
    const ushort* __restrict__ A, const ushort* __restrict__ Bt,
    float* __restrict__ C, int Kdim, int Ncols,
    ushort* __restrict__ Qo, ushort* __restrict__ Ko, ushort* __restrict__ Vo) {
  __shared__ __align__(16) ushort S[32768];
  ushort* SA = S;            // [2 buf][128 rows][64 elems]
  ushort* SB = S + 16384;

  const int tid = threadIdx.x, lane = tid & 63, w = tid >> 6;
  const int hs = lane >> 4, l15 = lane & 15;
  const int wm = w >> 1, wn = w & 1;

  // XCD-bijective swizzle of linear block id (nwg % 8 == 0 for both uses)
  const int gx = gridDim.x;
  const int nwg = gx * gridDim.y;
  const int bid = blockIdx.y * gx + blockIdx.x;
  const int id2 = (bid & 7) * (nwg >> 3) + (bid >> 3);
  const int brow = (id2 / gx) * 128, bcol = (id2 % gx) * 128;

  // staging map: gload g covers rows w*32+g*8+(lane>>3); source chunk is
  // pre-swizzled: (lane&7)^(lane>>3) (row&7 == lane>>3 since g*8 ≡ 0 mod 8)
  const int srow = w * 32 + (lane >> 3);
  const int sslot = ((lane & 7) ^ (lane >> 3)) * 8;
  const ushort* aS = A + (size_t)(brow + srow) * Kdim + sslot;
  const ushort* bS = Bt + (size_t)(bcol + srow) * Kdim + sslot;

  f32x4 acc[4][4];
  const f32x4 z4 = {0.f, 0.f, 0.f, 0.f};
#pragma unroll
  for (int i = 0; i < 4; ++i)
#pragma unroll
    for (int j = 0; j < 4; ++j) acc[i][j] = z4;

  // stage full 128x64 A and B tiles of K-tile T into buffer buf (8 gload_lds)
  auto STAGE = [&](int T, int buf) {
    ushort* la = SA + buf * 8192 + (w * 32) * 64;
    ushort* lb = SB + buf * 8192 + (w * 32) * 64;
#pragma unroll
    for (int g = 0; g < 4; ++g) {
      gload_lds16(aS + T * 64 + (size_t)(g * 8) * Kdim, la + g * 8 * 64);
      gload_lds16(bS + T * 64 + (size_t)(g * 8) * Kdim, lb + g * 8 * 64);
    }
  };

  // read both kk-halves' fragments (16 ds_read_b128); read chunk = c ^ (row&7)
  auto LOADF = [&](int buf, bf16x8 af[2][4], bf16x8 bf[2][4]) {
    const ushort* Ab = SA + buf * 8192;
    const ushort* Bb = SB + buf * 8192;
#pragma unroll
    for (int h = 0; h < 2; ++h) {
#pragma unroll
      for (int fr = 0; fr < 4; ++fr) {
        int r = wm * 64 + fr * 16 + l15;
        int c = (h * 4 + hs) ^ (r & 7);
        af[h][fr] = *(const bf16x8*)&Ab[r * 64 + c * 8];
      }
#pragma unroll
      for (int fc = 0; fc < 4; ++fc) {
        int r = wn * 64 + fc * 16 + l15;
        int c = (h * 4 + hs) ^ (r & 7);
        bf[h][fc] = *(const bf16x8*)&Bb[r * 64 + c * 8];
      }
    }
  };

  // prologue: stage tiles 0 and 1; retire tile 0 (counted), sync
  STAGE(0, 0);
  STAGE(1, 1);
  vmw<8>();
  __builtin_amdgcn_s_barrier();

#pragma unroll
  for (int t = 0; t < 8; ++t) {
    const int buf = t & 1;
    bf16x8 af[2][4], bf[2][4];
    LOADF(buf, af, bf);
    // drain this wave's ds_reads into registers before any wave overwrites buf
    asm volatile("s_waitcnt lgkmcnt(0)" ::: "memory");
    __builtin_amdgcn_sched_barrier(0);
    __builtin_amdgcn_s_barrier();          // all waves' reads of buf complete
    if (t < 6) STAGE(t + 2, buf);          // overwrite freed buffer
    __builtin_amdgcn_s_setprio(1);
#pragma unroll
    for (int h = 0; h < 2; ++h)
#pragma unroll
      for (int i = 0; i < 4; ++i)
#pragma unroll
        for (int j = 0; j < 4; ++j)
          acc[i][j] = __builtin_amdgcn_mfma_f32_16x16x32_bf16(af[h][i], bf[h][j], acc[i][j], 0, 0, 0);
    __builtin_amdgcn_s_setprio(0);
    // retire tile t+1's stage before next iteration reads it (counted)
    if (t < 6) vmw<8>(); else if (t == 6) vmw<0>();
    __builtin_amdgcn_s_barrier();
  }

#pragma unroll
  for (int i = 0; i < 4; ++i) {
    int row0 = brow + wm * 64 + i * 16 + hs * 4;
#pragma unroll
    for (int j = 0; j < 4; ++j) {
      int col = bcol + wn * 64 + j * 16 + l15;
      if (EPI == 0) {
#pragma unroll
        for (int q = 0; q < 4; ++q)
          C[(size_t)(row0 + q) * Ncols + col] = acc[i][j][q];
      } else {
        int m = col / 192, r = col % 192, which = r >> 6, dk = r & 63;
        ushort* base = (which == 0) ? Qo : (which == 1) ? Ko : Vo;
        float cs = (which == 0) ? QSCALE : 1.0f;
#pragma unroll
        for (int q = 0; q < 4; ++q) {
          int row = row0 + q;
          int bb = row >> 10, n = row & 1023;
          base[(size_t)((bb * 8 + m) * 1024 + n) * 64 + dk] = f2bf(acc[i][j][q] * cs);
        }
      }
    }
  }
}

// ---------------------------------------------------------------- V transpose
__global__ void __launch_bounds__(256) transpose_v_kernel(const ushort* __restrict__ V,
                                                          ushort* __restrict__ Vt) {
  __shared__ __align__(16) ushort T[64][72];
  int bm = blockIdx.x >> 4, nt = blockIdx.x & 15;
  const ushort* src = V + (size_t)bm * 65536 + nt * 64 * 64;
  int tid = threadIdx.x;
#pragma unroll
  for (int i = 0; i < 2; ++i) {
    int c = tid + i * 256;
    int row = c >> 3, cc = (c & 7) * 8;
    *(uint4*)&T[row][cc] = *(const uint4*)(src + c * 8);
  }
  __syncthreads();
  int v = tid >> 2, nn0 = (tid & 3) * 16;
  ushort tmp[16];
#pragma unroll
  for (int k = 0; k < 16; ++k) tmp[k] = T[nn0 + k][v];
  ushort* dst = Vt + (size_t)bm * 65536 + v * 1024 + nt * 64 + nn0;
  *(uint4*)(dst + 0) = *(uint4*)&tmp[0];
  *(uint4*)(dst + 8) = *(uint4*)&tmp[8];
}

// ---------------------------------------------------------------- flash attention v6
// (byte-identical to round 7/11/13: QBLK=64/wave, swapped QK^T, branchless
// no-max softmax in exp2 domain, l via all-ones MFMA on the matrix pipe)
__global__ void __launch_bounds__(256, 2) attn_kernel(const ushort* __restrict__ Q,
                                                      const ushort* __restrict__ K,
                                                      const ushort* __restrict__ Vt,
                                                      ushort* __restrict__ Hp) {
  __shared__ __align__(16) ushort Ks[2][64 * 64];
  __shared__ __align__(16) ushort Vs[2][64 * 64];

  int wk = (blockIdx.x & 7) * 64 + (blockIdx.x >> 3);
  const int bm = wk >> 2, qt = wk & 3;
  const int b = bm >> 3, m = bm & 7;
  const int tid = threadIdx.x, lane = tid & 63, w = tid >> 6;
  const int hi = lane >> 5, l31 = lane & 31;
  const ushort* Qp = Q + (size_t)bm * 65536;
  const ushort* Kp = K + (size_t)bm * 65536;
  const ushort* Vp = Vt + (size_t)bm * 65536;
  const int qw = qt * 256 + w * 64;

  bf16x8 qb[2][4];
#pragma unroll
  for (int qs = 0; qs < 2; ++qs)
#pragma unroll
    for (int s = 0; s < 4; ++s)
      qb[qs][s] = *(const bf16x8*)(Qp + (size_t)(qw + qs * 32 + l31) * 64 + s * 16 + hi * 8);

  bf16x8 ones;
#pragma unroll
  for (int j = 0; j < 8; ++j) ones[j] = (short)0x3F80;

  f32x16 oacc[2][2], lacc[2];
#pragma unroll
  for (int r = 0; r < 16; ++r) {
    oacc[0][0][r] = 0.f; oacc[0][1][r] = 0.f;
    oacc[1][0][r] = 0.f; oacc[1][1][r] = 0.f;
    lacc[0][r] = 0.f; lacc[1][r] = 0.f;
  }

  const int sr = tid >> 2, sc4 = (tid & 3) << 4;
  const unsigned bo0 = ((unsigned)(sc4 * 2)) ^ (((unsigned)(sr & 7)) << 4);

  {
    uint4 k0 = *(const uint4*)(Kp + (size_t)sr * 64 + sc4);
    uint4 k1 = *(const uint4*)(Kp + (size_t)sr * 64 + sc4 + 8);
    uint4 v0 = *(const uint4*)(Vp + (size_t)sr * 1024 + sc4);
    uint4 v1 = *(const uint4*)(Vp + (size_t)sr * 1024 + sc4 + 8);
    char* kd = (char*)&Ks[0][sr * 64];
    char* vd = (char*)&Vs[0][sr * 64];
    *(uint4*)(kd + bo0) = k0; *(uint4*)(kd + (bo0 ^ 16)) = k1;
    *(uint4*)(vd + bo0) = v0; *(uint4*)(vd + (bo0 ^ 16)) = v1;
  }
  __syncthreads();

  int cur = 0;
  for (int kt = 0; kt < 16; ++kt) {
    uint4 k0, k1, v0, v1;
    const bool pf = (kt < 15);
    if (pf) {
      int n0 = (kt + 1) * 64;
      k0 = *(const uint4*)(Kp + (size_t)(n0 + sr) * 64 + sc4);
      k1 = *(const uint4*)(Kp + (size_t)(n0 + sr) * 64 + sc4 + 8);
      v0 = *(const uint4*)(Vp + (size_t)sr * 1024 + n0 + sc4);
      v1 = *(const uint4*)(Vp + (size_t)sr * 1024 + n0 + sc4 + 8);
    }

    const ushort* kbase = &Ks[cur][0];
    bf16x8 kA[2][4];
#pragma unroll
    for (int ja = 0; ja < 2; ++ja) {
      int row = ja * 32 + l31;
      const char* kr = (const char*)(kbase + row * 64);
#pragma unroll
      for (int s = 0; s < 4; ++s)
        kA[ja][s] = *(const bf16x8*)(kr + (((unsigned)(s * 32 + hi * 16)) ^ (((unsigned)(row & 7)) << 4)));
    }

    f32x16 st[2][2];
#pragma unroll
    for (int qs = 0; qs < 2; ++qs)
#pragma unroll
      for (int ja = 0; ja < 2; ++ja) {
#pragma unroll
        for (int r = 0; r < 16; ++r) st[qs][ja][r] = 0.f;
#pragma unroll
        for (int s = 0; s < 4; ++s)
          st[qs][ja] = __builtin_amdgcn_mfma_f32_32x32x16_bf16(kA[ja][s], qb[qs][s], st[qs][ja], 0, 0, 0);
      }

    bf16x8 pb[2][4];
#pragma unroll
    for (int qs = 0; qs < 2; ++qs) {
#pragma unroll
      for (int r = 0; r < 16; ++r) {
        st[qs][0][r] = exp2_(st[qs][0][r]);
        st[qs][1][r] = exp2_(st[qs][1][r]);
      }

#pragma unroll
      for (int ja = 0; ja < 2; ++ja) {
#pragma unroll
        for (int g = 0; g < 2; ++g) {
          unsigned x0 = cvtpk(st[qs][ja][g * 8 + 0], st[qs][ja][g * 8 + 1]);
          unsigned x1 = cvtpk(st[qs][ja][g * 8 + 2], st[qs][ja][g * 8 + 3]);
          unsigned y0 = cvtpk(st[qs][ja][g * 8 + 4], st[qs][ja][g * 8 + 5]);
          unsigned y1 = cvtpk(st[qs][ja][g * 8 + 6], st[qs][ja][g * 8 + 7]);
          uint2v s0 = lane32_swap(x0, y0);
          uint2v s1 = lane32_swap(x1, y1);
          uint4 wv; wv.x = s0.x; wv.y = s1.x; wv.z = s0.y; wv.w = s1.y;
          pb[qs][ja * 2 + g] = *(bf16x8*)&wv;
        }
      }

#pragma unroll
      for (int ks = 0; ks < 4; ++ks)
        lacc[qs] = __builtin_amdgcn_mfma_f32_32x32x16_bf16(ones, pb[qs][ks], lacc[qs], 0, 0, 0);
    }

    const ushort* vbase = &Vs[cur][0];
#pragma unroll
    for (int vj = 0; vj < 2; ++vj) {
      int row = vj * 32 + l31;
      const char* vr = (const char*)(vbase + row * 64);
      bf16x8 va[4];
#pragma unroll
      for (int ks = 0; ks < 4; ++ks)
        va[ks] = *(const bf16x8*)(vr + (((unsigned)(ks * 32 + hi * 16)) ^ (((unsigned)(row & 7)) << 4)));
#pragma unroll
      for (int qs = 0; qs < 2; ++qs)
#pragma unroll
        for (int ks = 0; ks < 4; ++ks)
          oacc[qs][vj] = __builtin_amdgcn_mfma_f32_32x32x16_bf16(va[ks], pb[qs][ks], oacc[qs][vj], 0, 0, 0);
    }

    if (pf) {
      char* kd = (char*)&Ks[cur ^ 1][sr * 64];
      char* vd = (char*)&Vs[cur ^ 1][sr * 64];
      *(uint4*)(kd + bo0) = k0; *(uint4*)(kd + (bo0 ^ 16)) = k1;
      *(uint4*)(vd + bo0) = v0; *(uint4*)(vd + (bo0 ^ 16)) = v1;
    }
    __syncthreads();
    cur ^= 1;
  }

#pragma unroll
  for (int qs = 0; qs < 2; ++qs) {
    float linv = 1.0f / lacc[qs][0];
    int q = qw + qs * 32 + l31;
    size_t ro = ((size_t)b * 1024 + q) * 512 + m * 64;
#pragma unroll
    for (int vj = 0; vj < 2; ++vj)
#pragma unroll
      for (int t4 = 0; t4 < 4; ++t4) {
        ushort4 o;
        o.x = f2bf(oacc[qs][vj][t4 * 4 + 0] * linv);
        o.y = f2bf(oacc[qs][vj][t4 * 4 + 1] * linv);
        o.z = f2bf(oacc[qs][vj][t4 * 4 + 2] * linv);
        o.w = f2bf(oacc[qs][vj][t4 * 4 + 3] * linv);
        *(ushort4*)(Hp + ro + vj * 32 + t4 * 8 + hi * 4) = o;
      }
  }
}

// ---------------------------------------------------------------- launch
extern "C" void kernel_launch(void* const* d_in, const int* in_sizes, int n_in,
                              void* d_out, int out_size, void* d_ws, size_t ws_size,
                              hipStream_t stream) {
  const float* H  = (const float*)d_in[0];
  const float* WQ = (const float*)d_in[1];
  const float* WK = (const float*)d_in[2];
  const float* WV = (const float*)d_in[3];
  const float* WO = (const float*)d_in[4];
  float* out = (float*)d_out;

  ushort* ws   = (ushort*)d_ws;
  ushort* Hb   = ws;                         // 16384*512
  ushort* Wqkv = Hb + 16384 * 512;           // 1536*512
  ushort* Wo   = Wqkv + 1536 * 512;          // 512*512
  ushort* Qb   = Wo + 512 * 512;             // 128*1024*64
  ushort* Kb   = Qb + 128 * 1024 * 64;
  ushort* Vb   = Kb + 128 * 1024 * 64;
  ushort* Vtb  = Vb + 128 * 1024 * 64;
  ushort* Hp   = Vtb + 128 * 1024 * 64;      // 16384*512

  prep_kernel<<<8192, 256, 0, stream>>>(H, WQ, WK, WV, WO, Hb, Wqkv, Wo);
  gemm_bt_pipe<1><<<dim3(12, 128), 256, 0, stream>>>(Hb, Wqkv, nullptr, 512, 1536,
                                                     Qb, Kb, Vb);
  transpose_v_kernel<<<2048, 256, 0, stream>>>(Vb, Vtb);
  attn_kernel<<<512, 256, 0, stream>>>(Qb, Kb, Vtb, Hp);
  gemm_bt_pipe<0><<<dim3(4, 128), 256, 0, stream>>>(Hp, Wo, out, 512, 512,
                                                    nullptr, nullptr, nullptr);
}